// Round 9
// baseline (17902.818 us; speedup 1.0000x reference)
//
#include <hip/hip_runtime.h>
#include <math.h>

#define BB 2048
#define TT 512
#define NFEAT 25
#define UNITS 300
#define RPB 16
#define NBLK (BB/RPB)    // 128
#define NT 512
#define NW 8             // waves per block
#define NKS 11           // K-steps (352/32)
#define NTIL 80          // N'-tiles (1280/16), cols >=1200 pad
#define TPW 10           // tiles per wave (80/8 waves)
#define AROW 360         // Abf row stride (shorts)
#define GROW 72

#define OFF_B  0
#define SZ_B   (NTIL*NKS*512)        // 450560
#define OFF_M1 (OFF_B + SZ_B)
#define SZ_M1  (4*2*512)             // 4096
#define OFF_M2 (OFF_M1 + SZ_M1)
#define SZ_M2  (2*2*512)             // 2048
#define OFF_H  (OFF_M2 + SZ_M2)
#define SZ_H   (2*NKS*512)           // 11264
#define SW_SZ  (SZ_M1 + SZ_M2 + SZ_H)
#define SWM1   0
#define SWM2   (SZ_M1)
#define SWH    (SZ_M1 + SZ_M2)

typedef __attribute__((ext_vector_type(4))) float f32x4;
typedef __attribute__((ext_vector_type(8))) short bf16x8;

static __device__ __forceinline__ unsigned short f2bf(float f) {
    union { float f; unsigned u; } x; x.f = f;
    unsigned r = (x.u + 0x7fffu + ((x.u >> 16) & 1u)) >> 16;
    return (unsigned short)r;
}
static __device__ __forceinline__ float ftanh(float v) {
    float e = __builtin_amdgcn_exp2f(v * 2.8853900817779268f); // e^(2v)
    return 1.f - 2.f * __builtin_amdgcn_rcpf(e + 1.f);
}

// big-GEMM B: bf16 fragments, gate-interleaved columns col' = 4*u + gate
__global__ __launch_bounds__(256) void conv_big(
    const float* __restrict__ wk, const float* __restrict__ wr,
    unsigned short* __restrict__ dst)
{
    int idx = blockIdx.x * 256 + threadIdx.x;
    if (idx >= SZ_B) return;
    int j = idx & 7, n = (idx >> 3) & 15, kg = (idx >> 7) & 3, qq = idx >> 9;
    int ks = qq % NKS, nt = qq / NKS;
    int k = ks * 32 + kg * 8 + j, c = nt * 16 + n;
    float v = 0.f;
    if (c < 1200) {
        int oc = (c & 3) * 300 + (c >> 2);
        if (k < 25)       v = wk[k * 1200 + oc];
        else if (k < 325) v = wr[(k - 25) * 1200 + oc];
    }
    dst[OFF_B + idx] = f2bf(v);
}

__global__ __launch_bounds__(256) void conv_gen(
    const float* __restrict__ W, unsigned short* __restrict__ dst,
    int K, int N, int nks, int total)
{
    int idx = blockIdx.x * 256 + threadIdx.x;
    if (idx >= total) return;
    int j = idx & 7, n = (idx >> 3) & 15, kg = (idx >> 7) & 3, qq = idx >> 9;
    int ks = qq % nks, nt = qq / nks;
    int k = ks * 32 + kg * 8 + j, col = nt * 16 + n;
    float v = (k < K && col < N) ? W[k * N + col] : 0.f;
    dst[idx] = f2bf(v);
}

// heads B with K'=352 (k' = u+25, zeros at k'<25 and k'>=325)
__global__ __launch_bounds__(256) void conv_heads(
    const float* __restrict__ wa, const float* __restrict__ wm,
    const float* __restrict__ wsg, unsigned short* __restrict__ dst)
{
    int idx = blockIdx.x * 256 + threadIdx.x;
    if (idx >= SZ_H) return;
    int j = idx & 7, n = (idx >> 3) & 15, kg = (idx >> 7) & 3, qq = idx >> 9;
    int ks = qq % NKS, nt = qq / NKS;
    int k = ks * 32 + kg * 8 + j, col = nt * 16 + n;
    float v = 0.f;
    if (k >= 25 && k < 325 && col < 24) {
        int u = k - 25, h = col >> 3, m = col & 7;
        const float* W = (h == 0) ? wa : (h == 1) ? wm : wsg;
        v = W[u * 8 + m];
    }
    dst[OFF_H + idx] = f2bf(v);
}

#define MFMA __builtin_amdgcn_mfma_f32_16x16x32_bf16

__global__ __launch_bounds__(NT, 2)
void dilstm(
    const float* __restrict__ x,
    const unsigned short* __restrict__ wf,
    const float* __restrict__ bz,
    const float* __restrict__ b1v,
    const float* __restrict__ b2v,
    const float* __restrict__ ba,
    const float* __restrict__ bm,
    const float* __restrict__ bs,
    float* __restrict__ out)
{
    __shared__ unsigned short Abf[2][RPB][AROW]; // [0..23]=g, 24=comb, 25..324=h, 325.. = 0
    __shared__ unsigned short Gbf[RPB][GROW];    // gate-MLP input (K=50 pad 64)
    __shared__ unsigned short G1b[RPB][GROW];    // gate-MLP hidden
    __shared__ float Sc[RPB][24];
    __shared__ float BzS[1280];                  // bz in gate-interleaved col order
    __shared__ unsigned short SW[SW_SZ];         // staged MLP1|MLP2|heads weights

    const int t = threadIdx.x;
    const int lane = t & 63, wv = t >> 6;
    const int arow = lane & 15, akg = lane >> 4;
    const int crow0 = akg * 4;
    const int q4 = lane & 3, du = (lane >> 2) & 3;
    const int row0 = blockIdx.x * RPB;

    for (int i = t; i < 2 * RPB * AROW; i += NT) ((unsigned short*)Abf)[i] = 0;
    for (int i = t; i < RPB * GROW; i += NT) { ((unsigned short*)Gbf)[i] = 0; ((unsigned short*)G1b)[i] = 0; }
    for (int i = t; i < SW_SZ; i += NT) SW[i] = wf[OFF_M1 + i];
    for (int i = t; i < 1280; i += NT)
        BzS[i] = (i < 1200) ? bz[(i & 3) * 300 + (i >> 2)] : 0.f;

    // small biases (wave-role dependent)
    float m1bias = 0.f, m2bias = 0.f, hbias = 0.f;
    {
        int c1 = wv * 16 + arow;
        if (wv < 4 && c1 < 50) m1bias = b1v[c1];
        if (wv < 2 && c1 < 24) {
            m2bias = b2v[c1];
            hbias = (c1 < 8) ? ba[c1] : (c1 < 16) ? bm[c1 - 8] : bs[c1 - 16];
        }
    }

    float creg[TPW];
    #pragma unroll
    for (int i = 0; i < TPW; ++i) creg[i] = 0.f;

    const unsigned short* bbase = wf + OFF_B + (lane << 3);

    const int rA = t / 25, eA = t - (t / 25) * 25;
    float combreg = 0.f, xreg = 0.f;
    if (t < RPB * NFEAT) xreg = x[((size_t)(row0 + rA) * TT) * NFEAT + eA];
    __syncthreads();

    // initial gate-input build (prev = 0)
    if (t < RPB * NFEAT) {
        if (eA < 24) {
            Gbf[rA][eA] = f2bf(xreg);
        } else {
            float comb = xreg;
            combreg = comb;
            float denom = fmaxf(comb, 1e-8f);
            Gbf[rA][24] = f2bf(xreg / denom);
            Abf[0][rA][24] = f2bf(comb);
        }
    }
    __syncthreads();

    for (int ts = 0; ts < TT; ++ts) {
        const int p = ts & 1;

        // ---- MLP1 (waves 0-3, one 16-col tile each) ----
        if (wv < 4) {
            bf16x8 a0 = *(const bf16x8*)&Gbf[arow][akg * 8];
            bf16x8 a1 = *(const bf16x8*)&Gbf[arow][32 + akg * 8];
            bf16x8 b0 = *(const bf16x8*)&SW[SWM1 + (wv * 2 + 0) * 512 + (lane << 3)];
            bf16x8 b1 = *(const bf16x8*)&SW[SWM1 + (wv * 2 + 1) * 512 + (lane << 3)];
            f32x4 acc1 = {0.f, 0.f, 0.f, 0.f};
            acc1 = MFMA(a0, b0, acc1, 0, 0, 0);
            acc1 = MFMA(a1, b1, acc1, 0, 0, 0);
            int col = wv * 16 + arow;
            if (col < 50) {
                #pragma unroll
                for (int rg = 0; rg < 4; ++rg)
                    G1b[crow0 + rg][col] = f2bf(fmaxf(acc1[rg] + m1bias, 0.f));
            }
        }
        __syncthreads();

        // ---- MLP2 (waves 0-1) -> Abf[p][.][0..23] ----
        if (wv < 2) {
            bf16x8 a0 = *(const bf16x8*)&G1b[arow][akg * 8];
            bf16x8 a1 = *(const bf16x8*)&G1b[arow][32 + akg * 8];
            bf16x8 b0 = *(const bf16x8*)&SW[SWM2 + (wv * 2 + 0) * 512 + (lane << 3)];
            bf16x8 b1 = *(const bf16x8*)&SW[SWM2 + (wv * 2 + 1) * 512 + (lane << 3)];
            f32x4 acc2 = {0.f, 0.f, 0.f, 0.f};
            acc2 = MFMA(a0, b0, acc2, 0, 0, 0);
            acc2 = MFMA(a1, b1, acc2, 0, 0, 0);
            int col = wv * 16 + arow;
            if (col < 24) {
                #pragma unroll
                for (int rg = 0; rg < 4; ++rg)
                    Abf[p][crow0 + rg][col] = f2bf(acc2[rg] + m2bias);
            }
        }
        __syncthreads();

        // ---- big GEMM + fused cell: transient B loads ----
        {
            f32x4 acc[TPW];
            #pragma unroll
            for (int i = 0; i < TPW; ++i) acc[i] = (f32x4){0.f, 0.f, 0.f, 0.f};

            #pragma unroll
            for (int ks = 0; ks < NKS; ++ks) {
                bf16x8 aA = *(const bf16x8*)&Abf[p][arow][ks * 32 + akg * 8];
                #pragma unroll
                for (int i = 0; i < TPW; ++i) {
                    bf16x8 b = *(const bf16x8*)(bbase +
                        (size_t)(((wv + 8 * i) * NKS + ks) * 512));
                    acc[i] = MFMA(aA, b, acc[i], 0, 0, 0);
                }
            }

            if (t < RPB * NFEAT && ts + 1 < TT)
                xreg = x[((size_t)(row0 + rA) * TT + (ts + 1)) * NFEAT + eA];

            // per-tile: bias, 4-lane 4x4 transpose (gates->lanes), cell, h write
            #pragma unroll
            for (int i = 0; i < TPW; ++i) {
                float bzv = BzS[(wv + 8 * i) * 16 + arow];
                float a0 = acc[i][0] + bzv;
                float a1 = acc[i][1] + bzv;
                float a2 = acc[i][2] + bzv;
                float a3 = acc[i][3] + bzv;
                float x0 = __shfl_xor(a0, 1), x1 = __shfl_xor(a1, 1);
                float x2 = __shfl_xor(a2, 1), x3 = __shfl_xor(a3, 1);
                const bool mo = (lane & 1);
                float b0 = mo ? x1 : a0, b1 = mo ? a1 : x0;
                float b2 = mo ? x3 : a2, b3 = mo ? a3 : x2;
                float y0 = __shfl_xor(b0, 2), y1 = __shfl_xor(b1, 2);
                float y2 = __shfl_xor(b2, 2), y3 = __shfl_xor(b3, 2);
                const bool m2 = (lane & 2);
                float zi = m2 ? y2 : b0, zf = m2 ? y3 : b1;
                float zc = m2 ? b2 : y0, zo = m2 ? b3 : y1;
                if (wv + 8 * i < 75) {
                    float ig = fminf(fmaxf(0.2f * zi + 0.5f, 0.f), 1.f);
                    float fg = fminf(fmaxf(0.2f * zf + 0.5f, 0.f), 1.f);
                    float og = fminf(fmaxf(0.2f * zo + 0.5f, 0.f), 1.f);
                    float cn = fg * creg[i] + ig * ftanh(zc);
                    creg[i] = cn;
                    float hn = og * ftanh(cn);
                    Abf[p ^ 1][crow0 + q4][25 + (wv + 8 * i) * 4 + du] = f2bf(hn);
                }
            }
        }
        __syncthreads();

        // ---- heads (waves 0-1): Sc = h @ Wh + bias (K'=352, zero-padded) ----
        if (wv < 2) {
            f32x4 acc3 = {0.f, 0.f, 0.f, 0.f};
            #pragma unroll
            for (int ks = 0; ks < NKS; ++ks) {
                bf16x8 a = *(const bf16x8*)&Abf[p ^ 1][arow][ks * 32 + akg * 8];
                bf16x8 b = *(const bf16x8*)&SW[SWH + (wv * NKS + ks) * 512 + (lane << 3)];
                acc3 = MFMA(a, b, acc3, 0, 0, 0);
            }
            int col = wv * 16 + arow;
            if (col < 24) {
                #pragma unroll
                for (int rg = 0; rg < 4; ++rg)
                    Sc[crow0 + rg][col] = acc3[rg] + hbias;
            }
        }
        __syncthreads();

        // ---- softmax/nnelu + out + next-step gate input ----
        if (t < RPB * NFEAT) {
            float v;
            if (eA < 8) {
                float mx = Sc[rA][0];
                #pragma unroll
                for (int m = 1; m < 8; ++m) mx = fmaxf(mx, Sc[rA][m]);
                float sum = 0.f;
                #pragma unroll
                for (int m = 0; m < 8; ++m)
                    sum += __builtin_amdgcn_exp2f((Sc[rA][m] - mx) * 1.4426950408889634f);
                v = __builtin_amdgcn_exp2f((Sc[rA][eA] - mx) * 1.4426950408889634f) / sum;
            } else if (eA < 16) {
                v = Sc[rA][eA];
            } else if (eA < 24) {
                float s = Sc[rA][eA];
                v = (s > 0.f) ? (1.f + s) : __builtin_amdgcn_exp2f(s * 1.4426950408889634f);
            } else {
                v = combreg;
            }
            out[((size_t)(row0 + rA) * TT + ts) * NFEAT + eA] = v;
            if (eA < 24) {
                Gbf[rA][eA]      = f2bf(xreg);
                Gbf[rA][25 + eA] = f2bf(v);
            } else {
                float comb = xreg + combreg;
                float denom = fmaxf(comb, 1e-8f);
                Gbf[rA][24] = f2bf(xreg / denom);
                Gbf[rA][49] = f2bf(combreg / denom);
                Abf[p ^ 1][rA][24] = f2bf(comb);
                combreg = comb;
            }
        }
        __syncthreads();
    }
}

extern "C" void kernel_launch(void* const* d_in, const int* in_sizes, int n_in,
                              void* d_out, int out_size, void* d_ws, size_t ws_size,
                              hipStream_t stream) {
    const float* x   = (const float*)d_in[0];
    const float* wk  = (const float*)d_in[1];
    const float* wr  = (const float*)d_in[2];
    const float* bz  = (const float*)d_in[3];
    const float* w1  = (const float*)d_in[4];
    const float* b1  = (const float*)d_in[5];
    const float* w2  = (const float*)d_in[6];
    const float* b2  = (const float*)d_in[7];
    const float* wa  = (const float*)d_in[8];
    const float* ba  = (const float*)d_in[9];
    const float* wm  = (const float*)d_in[10];
    const float* bm  = (const float*)d_in[11];
    const float* wsg = (const float*)d_in[12];
    const float* bs  = (const float*)d_in[13];
    float* out = (float*)d_out;
    unsigned short* wf = (unsigned short*)d_ws;

    conv_big<<<(SZ_B + 255) / 256, 256, 0, stream>>>(wk, wr, wf);
    conv_gen<<<(SZ_M1 + 255) / 256, 256, 0, stream>>>(w1, wf + OFF_M1, 50, 50, 2, SZ_M1);
    conv_gen<<<(SZ_M2 + 255) / 256, 256, 0, stream>>>(w2, wf + OFF_M2, 50, 24, 2, SZ_M2);
    conv_heads<<<(SZ_H + 255) / 256, 256, 0, stream>>>(wa, wm, wsg, wf);
    dilstm<<<NBLK, NT, 0, stream>>>(x, wf, bz, b1, b2, ba, bm, bs, out);
}

// Round 10
// 5116.639 us; speedup vs baseline: 3.4989x; 3.4989x over previous
//
#include <hip/hip_runtime.h>
#include <math.h>

#define BB 2048
#define TT 512
#define NFEAT 25
#define UNITS 300
#define RPB 16
#define NBLK (BB/RPB)    // 128
#define NT 512
#define NW 8             // waves per block
#define NKS 11           // K-steps (352/32)
#define NTIL 80          // N'-tiles (1280/16), cols >=1200 pad
#define TPW 10           // tiles per wave (80/8 waves)
#define AROW 360         // Abf row stride (shorts)
#define GROW 72
#define WREG (NKS*TPW*512)   // per-wave B region: 56320 el

#define OFF_B  0
#define SZ_B   (NTIL*NKS*512)        // 450560
#define OFF_M1 (OFF_B + SZ_B)
#define SZ_M1  (4*2*512)             // 4096
#define OFF_M2 (OFF_M1 + SZ_M1)
#define SZ_M2  (2*2*512)             // 2048
#define OFF_H  (OFF_M2 + SZ_M2)
#define SZ_H   (2*NKS*512)           // 11264
#define SW_SZ  (SZ_M1 + SZ_M2 + SZ_H)
#define SWM1   0
#define SWM2   (SZ_M1)
#define SWH    (SZ_M1 + SZ_M2)

typedef __attribute__((ext_vector_type(4))) float f32x4;
typedef __attribute__((ext_vector_type(8))) short bf16x8;

static __device__ __forceinline__ unsigned short f2bf(float f) {
    union { float f; unsigned u; } x; x.f = f;
    unsigned r = (x.u + 0x7fffu + ((x.u >> 16) & 1u)) >> 16;
    return (unsigned short)r;
}
static __device__ __forceinline__ float ftanh(float v) {
    float e = __builtin_amdgcn_exp2f(v * 2.8853900817779268f); // e^(2v)
    return 1.f - 2.f * __builtin_amdgcn_rcpf(e + 1.f);
}

// big-GEMM B: bf16 fragments, [wave][ks][tile][512] layout, gate-interleaved
// columns col' = 4*u + gate. Wave w's tile i is global tile nt = w + 8*i.
__global__ __launch_bounds__(256) void conv_big(
    const float* __restrict__ wk, const float* __restrict__ wr,
    unsigned short* __restrict__ dst)
{
    int idx = blockIdx.x * 256 + threadIdx.x;
    if (idx >= SZ_B) return;
    int j = idx & 7, n = (idx >> 3) & 15, kg = (idx >> 7) & 3, qq = idx >> 9;
    int i = qq % TPW, ks = (qq / TPW) % NKS, w = qq / (TPW * NKS);
    int nt = w + 8 * i;
    int k = ks * 32 + kg * 8 + j, c = nt * 16 + n;
    float v = 0.f;
    if (c < 1200) {
        int oc = (c & 3) * 300 + (c >> 2);
        if (k < 25)       v = wk[k * 1200 + oc];
        else if (k < 325) v = wr[(k - 25) * 1200 + oc];
    }
    dst[OFF_B + idx] = f2bf(v);
}

__global__ __launch_bounds__(256) void conv_gen(
    const float* __restrict__ W, unsigned short* __restrict__ dst,
    int K, int N, int nks, int total)
{
    int idx = blockIdx.x * 256 + threadIdx.x;
    if (idx >= total) return;
    int j = idx & 7, n = (idx >> 3) & 15, kg = (idx >> 7) & 3, qq = idx >> 9;
    int ks = qq % nks, nt = qq / nks;
    int k = ks * 32 + kg * 8 + j, col = nt * 16 + n;
    float v = (k < K && col < N) ? W[k * N + col] : 0.f;
    dst[idx] = f2bf(v);
}

// heads B with K'=352 (k' = u+25, zeros at k'<25 and k'>=325)
__global__ __launch_bounds__(256) void conv_heads(
    const float* __restrict__ wa, const float* __restrict__ wm,
    const float* __restrict__ wsg, unsigned short* __restrict__ dst)
{
    int idx = blockIdx.x * 256 + threadIdx.x;
    if (idx >= SZ_H) return;
    int j = idx & 7, n = (idx >> 3) & 15, kg = (idx >> 7) & 3, qq = idx >> 9;
    int ks = qq % NKS, nt = qq / NKS;
    int k = ks * 32 + kg * 8 + j, col = nt * 16 + n;
    float v = 0.f;
    if (k >= 25 && k < 325 && col < 24) {
        int u = k - 25, h = col >> 3, m = col & 7;
        const float* W = (h == 0) ? wa : (h == 1) ? wm : wsg;
        v = W[u * 8 + m];
    }
    dst[OFF_H + idx] = f2bf(v);
}

#define MFMA __builtin_amdgcn_mfma_f32_16x16x32_bf16

__global__ __launch_bounds__(NT, 2)
void dilstm(
    const float* __restrict__ x,
    const unsigned short* __restrict__ wf,
    const float* __restrict__ bz,
    const float* __restrict__ b1v,
    const float* __restrict__ b2v,
    const float* __restrict__ ba,
    const float* __restrict__ bm,
    const float* __restrict__ bs,
    float* __restrict__ out)
{
    __shared__ unsigned short Abf[2][RPB][AROW]; // [0..23]=g, 24=comb, 25..324=h, 325.. = 0
    __shared__ unsigned short Gbf[RPB][GROW];    // gate-MLP input (K=50 pad 64)
    __shared__ unsigned short G1b[RPB][GROW];    // gate-MLP hidden
    __shared__ float Sc[RPB][24];
    __shared__ float BzS[1280];                  // bz in gate-interleaved col order
    __shared__ unsigned short SW[SW_SZ];         // staged MLP1|MLP2|heads weights

    const int t = threadIdx.x;
    const int lane = t & 63, wv = t >> 6;
    const int arow = lane & 15, akg = lane >> 4;
    const int crow0 = akg * 4;
    const int q4 = lane & 3, du = (lane >> 2) & 3;
    const int row0 = blockIdx.x * RPB;

    for (int i = t; i < 2 * RPB * AROW; i += NT) ((unsigned short*)Abf)[i] = 0;
    for (int i = t; i < RPB * GROW; i += NT) { ((unsigned short*)Gbf)[i] = 0; ((unsigned short*)G1b)[i] = 0; }
    for (int i = t; i < SW_SZ; i += NT) SW[i] = wf[OFF_M1 + i];
    for (int i = t; i < 1280; i += NT)
        BzS[i] = (i < 1200) ? bz[(i & 3) * 300 + (i >> 2)] : 0.f;

    // small biases (wave-role dependent)
    float m1bias = 0.f, m2bias = 0.f, hbias = 0.f;
    {
        int c1 = wv * 16 + arow;
        if (wv < 4 && c1 < 50) m1bias = b1v[c1];
        if (wv < 2 && c1 < 24) {
            m2bias = b2v[c1];
            hbias = (c1 < 8) ? ba[c1] : (c1 < 16) ? bm[c1 - 8] : bs[c1 - 16];
        }
    }

    float creg[TPW];
    #pragma unroll
    for (int i = 0; i < TPW; ++i) creg[i] = 0.f;

    // single per-wave B base; all GEMM loads stream sequentially from here
    const unsigned short* bwave = wf + OFF_B + (size_t)wv * WREG + (lane << 3);

    const int rA = t / 25, eA = t - (t / 25) * 25;
    float combreg = 0.f, xreg = 0.f;
    if (t < RPB * NFEAT) xreg = x[((size_t)(row0 + rA) * TT) * NFEAT + eA];
    __syncthreads();

    // initial gate-input build (prev = 0)
    if (t < RPB * NFEAT) {
        if (eA < 24) {
            Gbf[rA][eA] = f2bf(xreg);
        } else {
            float comb = xreg;
            combreg = comb;
            float denom = fmaxf(comb, 1e-8f);
            Gbf[rA][24] = f2bf(xreg / denom);
            Abf[0][rA][24] = f2bf(comb);
        }
    }
    __syncthreads();

    for (int ts = 0; ts < TT; ++ts) {
        const int p = ts & 1;

        // ---- MLP1 (waves 0-3, one 16-col tile each) ----
        if (wv < 4) {
            bf16x8 a0 = *(const bf16x8*)&Gbf[arow][akg * 8];
            bf16x8 a1 = *(const bf16x8*)&Gbf[arow][32 + akg * 8];
            bf16x8 b0 = *(const bf16x8*)&SW[SWM1 + (wv * 2 + 0) * 512 + (lane << 3)];
            bf16x8 b1 = *(const bf16x8*)&SW[SWM1 + (wv * 2 + 1) * 512 + (lane << 3)];
            f32x4 acc1 = {0.f, 0.f, 0.f, 0.f};
            acc1 = MFMA(a0, b0, acc1, 0, 0, 0);
            acc1 = MFMA(a1, b1, acc1, 0, 0, 0);
            int col = wv * 16 + arow;
            if (col < 50) {
                #pragma unroll
                for (int rg = 0; rg < 4; ++rg)
                    G1b[crow0 + rg][col] = f2bf(fmaxf(acc1[rg] + m1bias, 0.f));
            }
        }
        __syncthreads();

        // ---- MLP2 (waves 0-1) -> Abf[p][.][0..23] ----
        if (wv < 2) {
            bf16x8 a0 = *(const bf16x8*)&G1b[arow][akg * 8];
            bf16x8 a1 = *(const bf16x8*)&G1b[arow][32 + akg * 8];
            bf16x8 b0 = *(const bf16x8*)&SW[SWM2 + (wv * 2 + 0) * 512 + (lane << 3)];
            bf16x8 b1 = *(const bf16x8*)&SW[SWM2 + (wv * 2 + 1) * 512 + (lane << 3)];
            f32x4 acc2 = {0.f, 0.f, 0.f, 0.f};
            acc2 = MFMA(a0, b0, acc2, 0, 0, 0);
            acc2 = MFMA(a1, b1, acc2, 0, 0, 0);
            int col = wv * 16 + arow;
            if (col < 24) {
                #pragma unroll
                for (int rg = 0; rg < 4; ++rg)
                    Abf[p][crow0 + rg][col] = f2bf(acc2[rg] + m2bias);
            }
        }
        __syncthreads();

        // ---- big GEMM + fused cell: sequential B stream, one running pointer ----
        {
            f32x4 acc[TPW];
            #pragma unroll
            for (int i = 0; i < TPW; ++i) acc[i] = (f32x4){0.f, 0.f, 0.f, 0.f};

            const unsigned short* bp = bwave;
            #pragma unroll 1
            for (int ks = 0; ks < NKS; ++ks) {
                bf16x8 aA = *(const bf16x8*)&Abf[p][arow][ks * 32 + akg * 8];
                bf16x8 bb[TPW];
                #pragma unroll
                for (int i = 0; i < TPW; ++i)
                    bb[i] = *(const bf16x8*)(bp + i * 512);
                #pragma unroll
                for (int i = 0; i < TPW; ++i)
                    acc[i] = MFMA(aA, bb[i], acc[i], 0, 0, 0);
                bp += TPW * 512;
            }

            if (t < RPB * NFEAT && ts + 1 < TT)
                xreg = x[((size_t)(row0 + rA) * TT + (ts + 1)) * NFEAT + eA];

            // per-tile: bias, 4-lane 4x4 transpose (gates->lanes), cell, h write
            #pragma unroll
            for (int i = 0; i < TPW; ++i) {
                float bzv = BzS[(wv + 8 * i) * 16 + arow];
                float a0 = acc[i][0] + bzv;
                float a1 = acc[i][1] + bzv;
                float a2 = acc[i][2] + bzv;
                float a3 = acc[i][3] + bzv;
                float x0 = __shfl_xor(a0, 1), x1 = __shfl_xor(a1, 1);
                float x2 = __shfl_xor(a2, 1), x3 = __shfl_xor(a3, 1);
                const bool mo = (lane & 1);
                float b0 = mo ? x1 : a0, b1 = mo ? a1 : x0;
                float b2 = mo ? x3 : a2, b3 = mo ? a3 : x2;
                float y0 = __shfl_xor(b0, 2), y1 = __shfl_xor(b1, 2);
                float y2 = __shfl_xor(b2, 2), y3 = __shfl_xor(b3, 2);
                const bool m2 = (lane & 2);
                float zi = m2 ? y2 : b0, zf = m2 ? y3 : b1;
                float zc = m2 ? b2 : y0, zo = m2 ? b3 : y1;
                if (wv + 8 * i < 75) {
                    float ig = fminf(fmaxf(0.2f * zi + 0.5f, 0.f), 1.f);
                    float fg = fminf(fmaxf(0.2f * zf + 0.5f, 0.f), 1.f);
                    float og = fminf(fmaxf(0.2f * zo + 0.5f, 0.f), 1.f);
                    float cn = fg * creg[i] + ig * ftanh(zc);
                    creg[i] = cn;
                    float hn = og * ftanh(cn);
                    Abf[p ^ 1][crow0 + q4][25 + (wv + 8 * i) * 4 + du] = f2bf(hn);
                }
            }
        }
        __syncthreads();

        // ---- heads (waves 0-1): Sc = h @ Wh + bias (K'=352, zero-padded) ----
        if (wv < 2) {
            f32x4 acc3 = {0.f, 0.f, 0.f, 0.f};
            #pragma unroll
            for (int ks = 0; ks < NKS; ++ks) {
                bf16x8 a = *(const bf16x8*)&Abf[p ^ 1][arow][ks * 32 + akg * 8];
                bf16x8 b = *(const bf16x8*)&SW[SWH + (wv * NKS + ks) * 512 + (lane << 3)];
                acc3 = MFMA(a, b, acc3, 0, 0, 0);
            }
            int col = wv * 16 + arow;
            if (col < 24) {
                #pragma unroll
                for (int rg = 0; rg < 4; ++rg)
                    Sc[crow0 + rg][col] = acc3[rg] + hbias;
            }
        }
        __syncthreads();

        // ---- softmax/nnelu + out + next-step gate input ----
        if (t < RPB * NFEAT) {
            float v;
            if (eA < 8) {
                float mx = Sc[rA][0];
                #pragma unroll
                for (int m = 1; m < 8; ++m) mx = fmaxf(mx, Sc[rA][m]);
                float sum = 0.f;
                #pragma unroll
                for (int m = 0; m < 8; ++m)
                    sum += __builtin_amdgcn_exp2f((Sc[rA][m] - mx) * 1.4426950408889634f);
                v = __builtin_amdgcn_exp2f((Sc[rA][eA] - mx) * 1.4426950408889634f) / sum;
            } else if (eA < 16) {
                v = Sc[rA][eA];
            } else if (eA < 24) {
                float s = Sc[rA][eA];
                v = (s > 0.f) ? (1.f + s) : __builtin_amdgcn_exp2f(s * 1.4426950408889634f);
            } else {
                v = combreg;
            }
            out[((size_t)(row0 + rA) * TT + ts) * NFEAT + eA] = v;
            if (eA < 24) {
                Gbf[rA][eA]      = f2bf(xreg);
                Gbf[rA][25 + eA] = f2bf(v);
            } else {
                float comb = xreg + combreg;
                float denom = fmaxf(comb, 1e-8f);
                Gbf[rA][24] = f2bf(xreg / denom);
                Gbf[rA][49] = f2bf(combreg / denom);
                Abf[p ^ 1][rA][24] = f2bf(comb);
                combreg = comb;
            }
        }
        __syncthreads();
    }
}

extern "C" void kernel_launch(void* const* d_in, const int* in_sizes, int n_in,
                              void* d_out, int out_size, void* d_ws, size_t ws_size,
                              hipStream_t stream) {
    const float* x   = (const float*)d_in[0];
    const float* wk  = (const float*)d_in[1];
    const float* wr  = (const float*)d_in[2];
    const float* bz  = (const float*)d_in[3];
    const float* w1  = (const float*)d_in[4];
    const float* b1  = (const float*)d_in[5];
    const float* w2  = (const float*)d_in[6];
    const float* b2  = (const float*)d_in[7];
    const float* wa  = (const float*)d_in[8];
    const float* ba  = (const float*)d_in[9];
    const float* wm  = (const float*)d_in[10];
    const float* bm  = (const float*)d_in[11];
    const float* wsg = (const float*)d_in[12];
    const float* bs  = (const float*)d_in[13];
    float* out = (float*)d_out;
    unsigned short* wf = (unsigned short*)d_ws;

    conv_big<<<(SZ_B + 255) / 256, 256, 0, stream>>>(wk, wr, wf);
    conv_gen<<<(SZ_M1 + 255) / 256, 256, 0, stream>>>(w1, wf + OFF_M1, 50, 50, 2, SZ_M1);
    conv_gen<<<(SZ_M2 + 255) / 256, 256, 0, stream>>>(w2, wf + OFF_M2, 50, 24, 2, SZ_M2);
    conv_heads<<<(SZ_H + 255) / 256, 256, 0, stream>>>(wa, wm, wsg, wf);
    dilstm<<<NBLK, NT, 0, stream>>>(x, wf, bz, b1, b2, ba, bm, bs, out);
}